// Round 2
// baseline (190.429 us; speedup 1.0000x reference)
//
#include <hip/hip_runtime.h>
#include <math.h>
#include <stdint.h>

// Problem constants
#define BB    8
#define DIN   1024
#define TT    2048
#define KK    8192
#define DCB   8
#define NPOS  (BB*TT)         // 16384
#define KCHUNKS 64
#define KCH     (KK/KCHUNKS)  // 128
#define MARGIN  6e-4f         // >= 2*eps_bf16_screen(1.2e-4) + pack quant(6e-5), 2x headroom

// d_out layout (float32):
#define OFF_ZQOUT  0
#define OFF_COMMIT 16777216
#define OFF_CBLOSS 16777224
#define OFF_IDX    16777232
#define OFF_ZE     16793616

typedef short s8v __attribute__((ext_vector_type(8)));   // 8 bf16 in 4 VGPRs
typedef float f4v __attribute__((ext_vector_type(4)));

__device__ __forceinline__ unsigned short f2bf(float f) {
    unsigned u = __float_as_uint(f);
    u += 0x7FFF + ((u >> 16) & 1);          // round-to-nearest-even
    return (unsigned short)(u >> 16);
}
__device__ __forceinline__ float bf2f(unsigned short h) {
    return __uint_as_float(((unsigned)h) << 16);
}

// ---------------- kernel 1: prep (44 blocks, parallel roles) ----------------
// blocks 0..7: w_in rows (fp64 norm -> fp32 [i][o] layout); 8..11: w_out (fp32);
// 12..43: codebook (fp64 normalize + bf16 hi/lo mirror + skp).
// block 0 additionally zeroes the 64-slot fp64 loss accumulator.
__global__ __launch_bounds__(256) void k_prep(
    const float* __restrict__ in_v, const float* __restrict__ in_g,
    const float* __restrict__ out_v, const float* __restrict__ out_g,
    const float* __restrict__ cb,
    float* __restrict__ w_in_f, float* __restrict__ w_out_f,
    double* __restrict__ cb_n, double* __restrict__ s_k,
    unsigned short* __restrict__ cb16, float* __restrict__ skp_f,
    double* __restrict__ lacc)
{
    __shared__ double red[256];
    int tid = threadIdx.x;
    int blk = blockIdx.x;

    if (blk < 8) {
        if (blk == 0 && tid < 64) lacc[tid] = 0.0;
        int r = blk;
        double s = 0.0;
        for (int i = tid; i < DIN; i += 256) {
            double v = (double)in_v[r*DIN + i];
            s += v*v;
        }
        red[tid] = s; __syncthreads();
        for (int off = 128; off > 0; off >>= 1) {
            if (tid < off) red[tid] += red[tid+off];
            __syncthreads();
        }
        double scale = (double)in_g[r] / sqrt(red[0]);
        // transposed [i][o] fp32 layout for k_inproj's ds_read_b128 path
        for (int i = tid; i < DIN; i += 256)
            w_in_f[i*DCB + r] = (float)(scale * (double)in_v[r*DIN + i]);
    } else if (blk < 12) {
        int o = (blk-8)*256 + tid;
        float vv[DCB];
        double s = 0.0;
        #pragma unroll
        for (int d = 0; d < DCB; ++d) {
            vv[d] = out_v[o*DCB + d];
            s += (double)vv[d]*(double)vv[d];
        }
        double scale = (double)out_g[o] / sqrt(s);
        #pragma unroll
        for (int d = 0; d < DCB; ++d)
            w_out_f[o*DCB + d] = (float)(scale * (double)vv[d]);
    } else {
        int k = (blk-12)*256 + tid;
        double v[DCB]; double s = 0.0;
        #pragma unroll
        for (int d = 0; d < DCB; ++d) {
            v[d] = (double)cb[k*DCB + d];
            s += v[d]*v[d];
        }
        double nrm = sqrt(s);
        if (nrm < 1e-12) nrm = 1e-12;
        double s2 = 0.0;
        #pragma unroll
        for (int d = 0; d < DCB; ++d) {
            double t = v[d] / nrm;
            cb_n[(size_t)k*DCB + d] = t;
            s2 += t*t;
            float cf = (float)t;
            unsigned short bh = f2bf(cf);
            unsigned short bl = f2bf(cf - bf2f(bh));
            cb16[(size_t)k*16 + d]     = bh;
            cb16[(size_t)k*16 + 8 + d] = bl;
        }
        s_k[k] = s2;
        skp_f[k] = (float)(s2 + 4.0);   // shift => dist' = skp - 2*dot in [3,7] > 0
    }
}

// ---------------- kernel 2: fused in-projection + reduce (v2) ---------------
// Latency fix: float4 z loads (each thread owns 4 consecutive t), interleaved
// i-slices i = ii*32+q (32 independent, fully-unrollable iterations), fp32
// weights in LDS [i][o] (32 KB, conflict-free ds_read_b128), fp32 per-slice
// partials + fp64 cross-slice combine (total err ~3e-8 << ref fp32 noise 1e-6).
// NOTE: summation order is load-bearing for exact index match — do not reorder.
__global__ __launch_bounds__(256) void k_inproj(
    const float* __restrict__ z, const float* __restrict__ w_in_f,
    const float* __restrict__ in_b,
    float* __restrict__ ze_out, double* __restrict__ enc_n,
    double* __restrict__ q_s, unsigned short* __restrict__ enc16)
{
    __shared__ float sm[DIN*DCB];   // 32 KB: weights during loop, reduce buf after

    int tid = threadIdx.x;
    {   // stage fp32 weights (32 KB)
        const uint4* src = (const uint4*)w_in_f;
        uint4* dst = (uint4*)sm;
        #pragma unroll
        for (int x = 0; x < 8; ++x) dst[tid + 256*x] = src[tid + 256*x];
    }
    __syncthreads();

    int p = tid & 7;        // t-quad: positions pos0 + 4p .. 4p+3
    int q = tid >> 3;       // i-slice: i = ii*32 + q
    int pos0 = blockIdx.x*32;
    int b = pos0 >> 11, t0 = pos0 & (TT-1);

    const float* zp = z + ((size_t)b*DIN + q)*TT + t0 + p*4;

    float acc[DCB][4];
    #pragma unroll
    for (int o = 0; o < DCB; ++o)
        #pragma unroll
        for (int j = 0; j < 4; ++j) acc[o][j] = 0.f;

    #pragma unroll
    for (int ii = 0; ii < 32; ++ii) {
        f4v zv = *(const f4v*)(zp + (size_t)ii*32*TT);
        const f4v* wp = (const f4v*)(sm + (ii*32 + q)*DCB);
        f4v w0 = wp[0], w1 = wp[1];
        #pragma unroll
        for (int j = 0; j < 4; ++j) {
            acc[0][j] += w0[0]*zv[j];
            acc[1][j] += w0[1]*zv[j];
            acc[2][j] += w0[2]*zv[j];
            acc[3][j] += w0[3]*zv[j];
            acc[4][j] += w1[0]*zv[j];
            acc[5][j] += w1[1]*zv[j];
            acc[6][j] += w1[2]*zv[j];
            acc[7][j] += w1[3]*zv[j];
        }
    }

    // intra-wave butterfly over the 8 in-wave i-slices (lane bits 3..5)
    #pragma unroll
    for (int o = 0; o < DCB; ++o)
        #pragma unroll
        for (int j = 0; j < 4; ++j) {
            float v = acc[o][j];
            v += __shfl_xor(v, 8, 64);
            v += __shfl_xor(v, 16, 64);
            v += __shfl_xor(v, 32, 64);
            acc[o][j] = v;
        }

    __syncthreads();   // weights dead -> reuse sm as reduce buffer (4 KB used)
    int lane = tid & 63, wv = tid >> 6;
    if ((lane >> 3) == 0) {          // lanes 0..7 of each wave: p == lane
        float* rp = sm + wv*256 + p*32;
        #pragma unroll
        for (int o = 0; o < DCB; ++o)
            #pragma unroll
            for (int j = 0; j < 4; ++j) rp[o*4 + j] = acc[o][j];
    }
    __syncthreads();

    // final: thread -> (pos-in-block = tid>>3, o = tid&7); fp64 cross-wave sum
    int o2 = tid & 7, p32 = tid >> 3;
    double s = 0.0;
    #pragma unroll
    for (int w2 = 0; w2 < 4; ++w2)
        s += (double)sm[w2*256 + (p32 >> 2)*32 + o2*4 + (p32 & 3)];
    s += (double)in_b[o2];

    int pos = pos0 + p32;
    int b3 = pos >> 11, t3 = pos & (TT-1);
    ze_out[((size_t)b3*DCB + o2)*TT + t3] = (float)s;

    // per-pos normalize: the 8 lanes tid = p32*8 + o hold the 8 channels
    double n2 = s*s;
    n2 += __shfl_xor(n2, 1, 64);
    n2 += __shfl_xor(n2, 2, 64);
    n2 += __shfl_xor(n2, 4, 64);
    double nrm = sqrt(n2);
    if (nrm < 1e-12) nrm = 1e-12;
    double e = s / nrm;
    enc_n[(size_t)pos*DCB + o2] = e;
    double s2 = e*e;
    s2 += __shfl_xor(s2, 1, 64);
    s2 += __shfl_xor(s2, 2, 64);
    s2 += __shfl_xor(s2, 4, 64);
    if (o2 == 0) q_s[pos] = s2;

    float ef = (float)(-2.0 * e);      // A operand = -2*enc_n
    unsigned short ah = f2bf(ef);
    unsigned short al = f2bf(ef - bf2f(ah));
    enc16[(size_t)pos*16 + o2]     = ah;
    enc16[(size_t)pos*16 + 8 + o2] = al;
}

// ---------------- kernel 3: MFMA bf16 hi/lo argmin screen --------------------
// grid (256 q-blocks of 64, 8 chunk-groups of 8). One mfma_f32_16x16x32_bf16
// per 16q x 16n tile: K packed as A=[ah,al,ah,0] x B=[bh,bh,bl,*]
// => ah*bh + al*bh + ah*bl (residual al*bl bounded ~1.2e-4).
// skp (fp32-exact) enters via accumulator init. d1-only per chunk.
// Pack: key = bits|n (no AND). Since n<128, (bits|n)&~0x7F == bits&~0x7F, so
// the masked chunk-min and verify's scan mask are BIT-IDENTICAL to the
// AND-version; only the embedded winner-n differs, which verify ignores
// (full fp64 chunk rescan). Saves 4 VALU per MFMA.
#define SCR_QB 64
#define SCR_CB 8
__global__ __launch_bounds__(256) void k_screen(
    const unsigned short* __restrict__ enc16,
    const unsigned short* __restrict__ cb16,
    const float* __restrict__ skp_f,
    int* __restrict__ d1key)   // [q][KCHUNKS]
{
    __shared__ unsigned short cbl[SCR_CB*KCH*16];  // 32 KB
    __shared__ float skl[SCR_CB*KCH];              // 4 KB
    int tid = threadIdx.x;
    int cg = blockIdx.y;

    {   // stage 8 chunks of codebook bf16 + skp
        const uint4* src = (const uint4*)(cb16 + (size_t)cg*SCR_CB*KCH*16);
        uint4* dst = (uint4*)cbl;
        for (int x = tid; x < SCR_CB*KCH*2; x += 256) dst[x] = src[x];
        const float* ss = skp_f + cg*SCR_CB*KCH;
        for (int x = tid; x < SCR_CB*KCH; x += 256) skl[x] = ss[x];
    }
    __syncthreads();

    int lane = tid & 63;
    int wv   = tid >> 6;
    int col  = lane & 15, quad = lane >> 4;
    int qbase = blockIdx.x*SCR_QB + wv*16;

    // A fragment: lane holds A[m=col][k=quad*8+j]; quad 0,2 -> ah, 1 -> al, 3 -> 0
    s8v a;
    {
        const s8v* ap = (const s8v*)(enc16 + ((size_t)(qbase + col))*16 + (quad==1 ? 8 : 0));
        a = *ap;
        if (quad == 3) { s8v zz = {0,0,0,0,0,0,0,0}; a = zz; }
    }
    int bsel = (quad == 2) ? 1 : 0;   // B: quad 0,1 -> bh, 2 -> bl, 3 -> bh (A=0 there)

    for (int c2 = 0; c2 < SCR_CB; ++c2) {
        int d0 = 0x7F800000, d1r = 0x7F800000, d2r = 0x7F800000, d3r = 0x7F800000;
        const s8v* bp = (const s8v*)(cbl + c2*KCH*16);
        const float* sp = skl + c2*KCH;
        #pragma unroll
        for (int t = 0; t < 8; ++t) {
            int n = t*16 + col;
            s8v bfr = bp[n*2 + bsel];
            float sk = sp[n];
            f4v acc = {sk, sk, sk, sk};
            acc = __builtin_amdgcn_mfma_f32_16x16x32_bf16(a, bfr, acc, 0, 0, 0);
            // C layout: col = lane&15 (n), row = quad*4 + reg  -> OR 7-bit n into
            // the (positive) float bits; masked value unchanged vs AND-version.
            d0  = min(d0,  (int)(__float_as_uint(acc.x) | (unsigned)n));
            d1r = min(d1r, (int)(__float_as_uint(acc.y) | (unsigned)n));
            d2r = min(d2r, (int)(__float_as_uint(acc.z) | (unsigned)n));
            d3r = min(d3r, (int)(__float_as_uint(acc.w) | (unsigned)n));
        }
        // reduce over the 16 n-columns (lanes differing in low 4 bits)
        #pragma unroll
        for (int off = 1; off < 16; off <<= 1) {
            d0  = min(d0,  __shfl_xor(d0,  off, 64));
            d1r = min(d1r, __shfl_xor(d1r, off, 64));
            d2r = min(d2r, __shfl_xor(d2r, off, 64));
            d3r = min(d3r, __shfl_xor(d3r, off, 64));
        }
        if (col == 0) {
            int chunk = cg*SCR_CB + c2;
            int qrow  = qbase + quad*4;
            int* dst = d1key + (size_t)qrow*KCHUNKS + chunk;
            dst[0*KCHUNKS] = d0;
            dst[1*KCHUNKS] = d1r;
            dst[2*KCHUNKS] = d2r;
            dst[3*KCHUNKS] = d3r;
        }
    }
}

// ---------------- kernel 4: unified verify (fp64 exact) ---------------------
// One wave per query: read 64 chunk d1-keys (coalesced), fp64-rescan every
// chunk within MARGIN of the global best (always >= the winner's chunk),
// lexicographic first-min, write index. Per-block loss partial goes to a
// 64-slot fp64 atomic accumulator (512 adds/slot, no hotspot).
__global__ __launch_bounds__(256) void k_verify(
    const int* __restrict__ d1key,
    const double* __restrict__ enc_n, const double* __restrict__ q_s,
    const double* __restrict__ cb_n, const double* __restrict__ s_k,
    const float* __restrict__ cb, const float* __restrict__ ze,
    float* __restrict__ idx_f, int* __restrict__ idx_i,
    double* __restrict__ lacc)
{
    __shared__ double sred[4];
    int tid = threadIdx.x;
    int lane = tid & 63;
    int wv = tid >> 6;
    int pos = blockIdx.x*4 + wv;

    int myk = d1key[(size_t)pos*KCHUNKS + lane];   // lane = chunk id
    int m = myk;
    #pragma unroll
    for (int off = 1; off < 64; off <<= 1) m = min(m, __shfl_xor(m, off, 64));
    float thr = __int_as_float(m & 0xFFFFFF80) + MARGIN;
    bool scan = __int_as_float(myk & 0xFFFFFF80) <= thr;
    unsigned long long mask = __ballot(scan);

    double e[DCB];
    #pragma unroll
    for (int d = 0; d < DCB; ++d) e[d] = enc_n[(size_t)pos*DCB + d];
    double qs = q_s[pos];

    double bd = 1e300; int bi = 0x7FFFFFFF;
    while (mask) {
        int c = __ffsll((long long)mask) - 1;
        mask &= mask - 1;
        #pragma unroll
        for (int r = 0; r < KCH/64; ++r) {
            int k = c*KCH + r*64 + lane;
            const double* cp = cb_n + (size_t)k*DCB;
            double dot = e[0]*cp[0] + e[1]*cp[1] + e[2]*cp[2] + e[3]*cp[3]
                       + e[4]*cp[4] + e[5]*cp[5] + e[6]*cp[6] + e[7]*cp[7];
            double dist = qs - 2.0*dot + s_k[k];
            if (dist < bd || (dist == bd && k < bi)) { bd = dist; bi = k; }
        }
    }
    #pragma unroll
    for (int off = 1; off < 64; off <<= 1) {
        double od = __shfl_xor(bd, off, 64);
        int    oi = __shfl_xor(bi, off, 64);
        if (od < bd || (od == bd && oi < bi)) { bd = od; bi = oi; }
    }
    if (lane == 0) {
        int b = pos >> 11, t = pos & (TT-1);
        idx_f[pos] = (float)bi;
        idx_i[pos] = bi;
        double ssum = 0.0;
        #pragma unroll
        for (int d = 0; d < DCB; ++d) {
            double zev = (double)ze[((size_t)b*DCB + d)*TT + t];
            double zqv = (double)cb[bi*DCB + d];
            double diff = zev - zqv;
            ssum += diff*diff;
        }
        sred[wv] = ssum;
    }
    __syncthreads();
    if (tid == 0) {
        double t4 = sred[0] + sred[1] + sred[2] + sred[3];
        int b = (blockIdx.x*4) >> 11;     // all 4 pos in a block share b
        atomicAdd(&lacc[b*8 + (blockIdx.x & 7)], t4);
    }
}

// ---------------- kernel 5: out-projection (+ loss finalize) ----------------
// grid (NPOS/256, DIN/64) = 1024 blocks -> 4 blocks/CU for write-BW overlap.
__global__ __launch_bounds__(256) void k_out_proj(
    const float* __restrict__ cb, const float* __restrict__ ze,
    const int* __restrict__ idx_i, const float* __restrict__ w_out,
    const float* __restrict__ out_b, const double* __restrict__ lacc,
    float* __restrict__ commit_out, float* __restrict__ cbloss_out,
    float* __restrict__ zq_out)
{
    __shared__ float wl[64*DCB];
    __shared__ float bl[64];
    int tid = threadIdx.x;

    if (blockIdx.x == 0 && blockIdx.y == 0 && tid < 8) {
        double s = 0.0;
        #pragma unroll
        for (int j = 0; j < 8; ++j) s += lacc[tid*8 + j];
        double mm = s / (double)(DCB*TT);
        commit_out[tid] = (float)(mm * 0.005);
        cbloss_out[tid] = (float)mm;
    }

    int oc = blockIdx.y;
    int obase = oc*64;
    for (int x = tid; x < 64*DCB; x += 256) wl[x] = w_out[obase*DCB + x];
    if (tid < 64) bl[tid] = out_b[obase + tid];
    __syncthreads();

    int pos = blockIdx.x*256 + tid;
    int b = pos >> 11, t = pos & (TT-1);
    int ki = idx_i[pos];
    float zq[DCB];
    #pragma unroll
    for (int d = 0; d < DCB; ++d) {
        float zev = ze[((size_t)b*DCB + d)*TT + t];
        float zqv = cb[ki*DCB + d];
        zq[d] = zev + (zqv - zev);
    }
    float* outp = zq_out + ((size_t)b*DIN + obase)*TT + t;
    for (int oo = 0; oo < 64; ++oo) {
        float acc = 0.f;
        #pragma unroll
        for (int d = 0; d < DCB; ++d) acc += wl[oo*DCB + d]*zq[d];
        acc += bl[oo];
        outp[(size_t)oo*TT] = acc;
    }
}

// ---------------- launch ----------------------------------------------------
extern "C" void kernel_launch(void* const* d_in, const int* in_sizes, int n_in,
                              void* d_out, int out_size, void* d_ws, size_t ws_size,
                              hipStream_t stream)
{
    const float* z        = (const float*)d_in[0];
    const float* in_v     = (const float*)d_in[1];
    const float* in_g     = (const float*)d_in[2];
    const float* in_b     = (const float*)d_in[3];
    const float* out_v    = (const float*)d_in[4];
    const float* out_g    = (const float*)d_in[5];
    const float* out_b    = (const float*)d_in[6];
    const float* codebook = (const float*)d_in[7];

    float* out = (float*)d_out;
    float* zq_out_p  = out + OFF_ZQOUT;
    float* commit_p  = out + OFF_COMMIT;
    float* cbloss_p  = out + OFF_CBLOSS;
    float* idx_p     = out + OFF_IDX;
    float* ze_p      = out + OFF_ZE;

    // workspace layout (doubles first; w_in slot holds fp32 [i][o] weights)
    float*  w_in_f = (float*)d_ws;                         // in 8192-dbl slot
    double* cb_n   = (double*)d_ws + DCB*DIN;              // 65536
    double* s_k    = cb_n + (size_t)KK*DCB;                // 8192
    double* enc_n  = s_k + KK;                             // 131072
    double* q_s    = enc_n + (size_t)NPOS*DCB;             // 16384
    double* loss_q = q_s + NPOS;                           // 16384 (slot kept, unused)
    float*  w_out  = (float*)(loss_q + NPOS);              // 8192
    float*  skp_f  = w_out + DCB*DIN;                      // 8192
    unsigned short* cb16  = (unsigned short*)(skp_f + KK); // 131072 ushorts
    unsigned short* enc16 = cb16 + (size_t)KK*16;          // 262144 ushorts
    int*    d1key  = (int*)(enc16 + (size_t)NPOS*16);      // NPOS*64 ints (4 MB)
    int*    idx_i  = d1key + (size_t)NPOS*KCHUNKS;         // 16384
    double* lacc   = (double*)(idx_i + NPOS);              // 64 fp64 loss slots

    k_prep<<<44, 256, 0, stream>>>(in_v, in_g, out_v, out_g, codebook,
                                   w_in_f, w_out, cb_n, s_k, cb16, skp_f, lacc);
    k_inproj<<<NPOS/32, 256, 0, stream>>>(z, w_in_f, in_b, ze_p, enc_n, q_s, enc16);
    k_screen<<<dim3(NPOS/SCR_QB, KCHUNKS/SCR_CB), 256, 0, stream>>>(
        enc16, cb16, skp_f, d1key);
    k_verify<<<NPOS/4, 256, 0, stream>>>(d1key, enc_n, q_s, cb_n, s_k,
                                         codebook, ze_p, idx_p, idx_i, lacc);
    k_out_proj<<<dim3(NPOS/256, DIN/64), 256, 0, stream>>>(
        codebook, ze_p, idx_i, w_out, out_b, lacc, commit_p, cbloss_p, zq_out_p);
}

// Round 3
// 179.278 us; speedup vs baseline: 1.0622x; 1.0622x over previous
//
#include <hip/hip_runtime.h>
#include <math.h>
#include <stdint.h>

// Problem constants
#define BB    8
#define DIN   1024
#define TT    2048
#define KK    8192
#define DCB   8
#define NPOS  (BB*TT)         // 16384
#define KCHUNKS 64
#define KCH     (KK/KCHUNKS)  // 128
#define MARGIN  6e-4f         // screen now exact to ~1e-5 (full hi/lo cross terms); 6e-4 is ample

// d_out layout (float32):
#define OFF_ZQOUT  0
#define OFF_COMMIT 16777216
#define OFF_CBLOSS 16777224
#define OFF_IDX    16777232
#define OFF_ZE     16793616

typedef short s8v __attribute__((ext_vector_type(8)));   // 8 bf16 in 4 VGPRs
typedef float f4v __attribute__((ext_vector_type(4)));

__device__ __forceinline__ unsigned short f2bf(float f) {
    unsigned u = __float_as_uint(f);
    u += 0x7FFF + ((u >> 16) & 1);          // round-to-nearest-even
    return (unsigned short)(u >> 16);
}
__device__ __forceinline__ float bf2f(unsigned short h) {
    return __uint_as_float(((unsigned)h) << 16);
}

// ---------------- kernel 1: prep (44 blocks, parallel roles) ----------------
// blocks 0..7: w_in rows (fp64 norm -> fp32 [i][o] layout); 8..11: w_out (fp32);
// 12..43: codebook (fp64 normalize + bf16 hi/lo mirror + skp).
// block 0 additionally zeroes the 64-slot fp64 loss accumulator.
__global__ __launch_bounds__(256) void k_prep(
    const float* __restrict__ in_v, const float* __restrict__ in_g,
    const float* __restrict__ out_v, const float* __restrict__ out_g,
    const float* __restrict__ cb,
    float* __restrict__ w_in_f, float* __restrict__ w_out_f,
    double* __restrict__ cb_n, double* __restrict__ s_k,
    unsigned short* __restrict__ cb16, float* __restrict__ skp_f,
    double* __restrict__ lacc)
{
    __shared__ double red[256];
    int tid = threadIdx.x;
    int blk = blockIdx.x;

    if (blk < 8) {
        if (blk == 0 && tid < 64) lacc[tid] = 0.0;
        int r = blk;
        double s = 0.0;
        for (int i = tid; i < DIN; i += 256) {
            double v = (double)in_v[r*DIN + i];
            s += v*v;
        }
        red[tid] = s; __syncthreads();
        for (int off = 128; off > 0; off >>= 1) {
            if (tid < off) red[tid] += red[tid+off];
            __syncthreads();
        }
        double scale = (double)in_g[r] / sqrt(red[0]);
        // transposed [i][o] fp32 layout for k_inproj's ds_read_b128 path
        for (int i = tid; i < DIN; i += 256)
            w_in_f[i*DCB + r] = (float)(scale * (double)in_v[r*DIN + i]);
    } else if (blk < 12) {
        int o = (blk-8)*256 + tid;
        float vv[DCB];
        double s = 0.0;
        #pragma unroll
        for (int d = 0; d < DCB; ++d) {
            vv[d] = out_v[o*DCB + d];
            s += (double)vv[d]*(double)vv[d];
        }
        double scale = (double)out_g[o] / sqrt(s);
        #pragma unroll
        for (int d = 0; d < DCB; ++d)
            w_out_f[o*DCB + d] = (float)(scale * (double)vv[d]);
    } else {
        int k = (blk-12)*256 + tid;
        double v[DCB]; double s = 0.0;
        #pragma unroll
        for (int d = 0; d < DCB; ++d) {
            v[d] = (double)cb[k*DCB + d];
            s += v[d]*v[d];
        }
        double nrm = sqrt(s);
        if (nrm < 1e-12) nrm = 1e-12;
        double s2 = 0.0;
        #pragma unroll
        for (int d = 0; d < DCB; ++d) {
            double t = v[d] / nrm;
            cb_n[(size_t)k*DCB + d] = t;
            s2 += t*t;
            float cf = (float)t;
            unsigned short bh = f2bf(cf);
            unsigned short bl = f2bf(cf - bf2f(bh));
            cb16[(size_t)k*16 + d]     = bh;
            cb16[(size_t)k*16 + 8 + d] = bl;
        }
        s_k[k] = s2;
        skp_f[k] = (float)(s2 + 4.0);   // shift => dist' = skp - 2*dot in [3,7] > 0
    }
}

// ---------------- kernel 2: fused in-projection + reduce (v2) ---------------
// NOTE: summation order is load-bearing for exact index match — do not reorder.
__global__ __launch_bounds__(256) void k_inproj(
    const float* __restrict__ z, const float* __restrict__ w_in_f,
    const float* __restrict__ in_b,
    float* __restrict__ ze_out, double* __restrict__ enc_n,
    double* __restrict__ q_s, unsigned short* __restrict__ enc16)
{
    __shared__ float sm[DIN*DCB];   // 32 KB: weights during loop, reduce buf after

    int tid = threadIdx.x;
    {   // stage fp32 weights (32 KB)
        const uint4* src = (const uint4*)w_in_f;
        uint4* dst = (uint4*)sm;
        #pragma unroll
        for (int x = 0; x < 8; ++x) dst[tid + 256*x] = src[tid + 256*x];
    }
    __syncthreads();

    int p = tid & 7;        // t-quad: positions pos0 + 4p .. 4p+3
    int q = tid >> 3;       // i-slice: i = ii*32 + q
    int pos0 = blockIdx.x*32;
    int b = pos0 >> 11, t0 = pos0 & (TT-1);

    const float* zp = z + ((size_t)b*DIN + q)*TT + t0 + p*4;

    float acc[DCB][4];
    #pragma unroll
    for (int o = 0; o < DCB; ++o)
        #pragma unroll
        for (int j = 0; j < 4; ++j) acc[o][j] = 0.f;

    #pragma unroll
    for (int ii = 0; ii < 32; ++ii) {
        f4v zv = *(const f4v*)(zp + (size_t)ii*32*TT);
        const f4v* wp = (const f4v*)(sm + (ii*32 + q)*DCB);
        f4v w0 = wp[0], w1 = wp[1];
        #pragma unroll
        for (int j = 0; j < 4; ++j) {
            acc[0][j] += w0[0]*zv[j];
            acc[1][j] += w0[1]*zv[j];
            acc[2][j] += w0[2]*zv[j];
            acc[3][j] += w0[3]*zv[j];
            acc[4][j] += w1[0]*zv[j];
            acc[5][j] += w1[1]*zv[j];
            acc[6][j] += w1[2]*zv[j];
            acc[7][j] += w1[3]*zv[j];
        }
    }

    // intra-wave butterfly over the 8 in-wave i-slices (lane bits 3..5)
    #pragma unroll
    for (int o = 0; o < DCB; ++o)
        #pragma unroll
        for (int j = 0; j < 4; ++j) {
            float v = acc[o][j];
            v += __shfl_xor(v, 8, 64);
            v += __shfl_xor(v, 16, 64);
            v += __shfl_xor(v, 32, 64);
            acc[o][j] = v;
        }

    __syncthreads();   // weights dead -> reuse sm as reduce buffer (4 KB used)
    int lane = tid & 63, wv = tid >> 6;
    if ((lane >> 3) == 0) {          // lanes 0..7 of each wave: p == lane
        float* rp = sm + wv*256 + p*32;
        #pragma unroll
        for (int o = 0; o < DCB; ++o)
            #pragma unroll
            for (int j = 0; j < 4; ++j) rp[o*4 + j] = acc[o][j];
    }
    __syncthreads();

    // final: thread -> (pos-in-block = tid>>3, o = tid&7); fp64 cross-wave sum
    int o2 = tid & 7, p32 = tid >> 3;
    double s = 0.0;
    #pragma unroll
    for (int w2 = 0; w2 < 4; ++w2)
        s += (double)sm[w2*256 + (p32 >> 2)*32 + o2*4 + (p32 & 3)];
    s += (double)in_b[o2];

    int pos = pos0 + p32;
    int b3 = pos >> 11, t3 = pos & (TT-1);
    ze_out[((size_t)b3*DCB + o2)*TT + t3] = (float)s;

    // per-pos normalize: the 8 lanes tid = p32*8 + o hold the 8 channels
    double n2 = s*s;
    n2 += __shfl_xor(n2, 1, 64);
    n2 += __shfl_xor(n2, 2, 64);
    n2 += __shfl_xor(n2, 4, 64);
    double nrm = sqrt(n2);
    if (nrm < 1e-12) nrm = 1e-12;
    double e = s / nrm;
    enc_n[(size_t)pos*DCB + o2] = e;
    double s2 = e*e;
    s2 += __shfl_xor(s2, 1, 64);
    s2 += __shfl_xor(s2, 2, 64);
    s2 += __shfl_xor(s2, 4, 64);
    if (o2 == 0) q_s[pos] = s2;

    float ef = (float)(-2.0 * e);      // A operand = -2*enc_n
    unsigned short ah = f2bf(ef);
    unsigned short al = f2bf(ef - bf2f(ah));
    enc16[(size_t)pos*16 + o2]     = ah;
    enc16[(size_t)pos*16 + 8 + o2] = al;
}

// ---------------- kernel 3: MFMA screen v3 (transposed operands) ------------
// A = codebook (M = n-rows, from LDS hi/lo planes), B = queries (N = q-cols,
// in registers). k-quads: A=[ch,cl,ch,cl], B=[eh,eh,el,el] => full
// (ch+cl)(eh+el) product — exact to fp32 accumulation (~1e-5), no OR-pack.
// C: col=lane&15=q, row=quad*4+reg=n  => n-reduction is IN-LANE (min3 over
// regs), cross-lane only 2 shfl per fragment per chunk. A-read: 16B-stride
// planes = 2-way bank (free), shared by 4 query-fragments (64 q per wave).
// d1key = raw positive-float bits; verify masks low 7 bits (mask-compatible
// with the old packed keys).
#define SCR_CB 8
__global__ __launch_bounds__(256) void k_screen(
    const unsigned short* __restrict__ enc16,
    const unsigned short* __restrict__ cb16,
    const float* __restrict__ skp_f,
    int* __restrict__ d1key)   // [q][KCHUNKS]
{
    __shared__ unsigned short cbh[SCR_CB*KCH*8];   // hi plane, 16 KB
    __shared__ unsigned short cbl[SCR_CB*KCH*8];   // lo plane, 16 KB
    __shared__ float skl[SCR_CB*KCH];              // 4 KB
    int tid = threadIdx.x;
    int cg = blockIdx.y;

    {   // stage 8 chunks: de-interleave hi|lo uint4 pairs into planes
        const uint4* src = (const uint4*)(cb16 + (size_t)cg*SCR_CB*KCH*16);
        uint4* dh = (uint4*)cbh;
        uint4* dl = (uint4*)cbl;
        #pragma unroll
        for (int x = 0; x < 4; ++x) {
            int n = tid + 256*x;
            dh[n] = src[2*n];
            dl[n] = src[2*n + 1];
        }
        const float* ss = skp_f + (size_t)cg*SCR_CB*KCH;
        #pragma unroll
        for (int x = 0; x < 4; ++x) skl[tid + 256*x] = ss[tid + 256*x];
    }
    __syncthreads();

    int lane = tid & 63;
    int wv   = tid >> 6;
    int col  = lane & 15, quad = lane >> 4;
    int qbase = blockIdx.x*256 + wv*64;

    // B-frags: lane supplies B[k=quad*8+j][q=col]; quads 0,1 -> eh, 2,3 -> el
    s8v bfr[4];
    #pragma unroll
    for (int f = 0; f < 4; ++f)
        bfr[f] = *(const s8v*)(enc16 + ((size_t)(qbase + f*16 + col))*16 + (quad >= 2 ? 8 : 0));

    // A-plane for this lane: quads 0,2 -> hi, quads 1,3 -> lo
    const unsigned short* aplane = (quad & 1) ? cbl : cbh;

    for (int c2 = 0; c2 < SCR_CB; ++c2) {
        float dmin0 = INFINITY, dmin1 = INFINITY, dmin2 = INFINITY, dmin3 = INFINITY;
        #pragma unroll
        for (int t = 0; t < 8; ++t) {
            int nb = c2*KCH + t*16;
            s8v a = *(const s8v*)(aplane + (size_t)(nb + col)*8);
            f4v sk4 = *(const f4v*)(skl + nb + quad*4);   // C-init = skp[row]
            f4v acc;
            acc = __builtin_amdgcn_mfma_f32_16x16x32_bf16(a, bfr[0], sk4, 0, 0, 0);
            dmin0 = fminf(dmin0, fminf(fminf(acc.x, acc.y), fminf(acc.z, acc.w)));
            acc = __builtin_amdgcn_mfma_f32_16x16x32_bf16(a, bfr[1], sk4, 0, 0, 0);
            dmin1 = fminf(dmin1, fminf(fminf(acc.x, acc.y), fminf(acc.z, acc.w)));
            acc = __builtin_amdgcn_mfma_f32_16x16x32_bf16(a, bfr[2], sk4, 0, 0, 0);
            dmin2 = fminf(dmin2, fminf(fminf(acc.x, acc.y), fminf(acc.z, acc.w)));
            acc = __builtin_amdgcn_mfma_f32_16x16x32_bf16(a, bfr[3], sk4, 0, 0, 0);
            dmin3 = fminf(dmin3, fminf(fminf(acc.x, acc.y), fminf(acc.z, acc.w)));
        }
        int chunk = cg*SCR_CB + c2;
        float dm[4] = {dmin0, dmin1, dmin2, dmin3};
        #pragma unroll
        for (int f = 0; f < 4; ++f) {
            float v = dm[f];
            v = fminf(v, __shfl_xor(v, 16, 64));
            v = fminf(v, __shfl_xor(v, 32, 64));
            if (quad == 0)
                d1key[(size_t)(qbase + f*16 + col)*KCHUNKS + chunk] = __float_as_int(v);
        }
    }
}

// ---------------- kernel 4: unified verify (fp64 exact) ---------------------
// One wave per query: read 64 chunk d1-keys (coalesced), fp64-rescan every
// chunk within MARGIN of the global best (always >= the winner's chunk),
// lexicographic first-min, write index. Per-block loss partial goes to a
// 64-slot fp64 atomic accumulator (512 adds/slot, no hotspot).
__global__ __launch_bounds__(256) void k_verify(
    const int* __restrict__ d1key,
    const double* __restrict__ enc_n, const double* __restrict__ q_s,
    const double* __restrict__ cb_n, const double* __restrict__ s_k,
    const float* __restrict__ cb, const float* __restrict__ ze,
    float* __restrict__ idx_f, int* __restrict__ idx_i,
    double* __restrict__ lacc)
{
    __shared__ double sred[4];
    int tid = threadIdx.x;
    int lane = tid & 63;
    int wv = tid >> 6;
    int pos = blockIdx.x*4 + wv;

    int myk = d1key[(size_t)pos*KCHUNKS + lane];   // lane = chunk id
    int m = myk;
    #pragma unroll
    for (int off = 1; off < 64; off <<= 1) m = min(m, __shfl_xor(m, off, 64));
    float thr = __int_as_float(m & 0xFFFFFF80) + MARGIN;
    bool scan = __int_as_float(myk & 0xFFFFFF80) <= thr;
    unsigned long long mask = __ballot(scan);

    double e[DCB];
    #pragma unroll
    for (int d = 0; d < DCB; ++d) e[d] = enc_n[(size_t)pos*DCB + d];
    double qs = q_s[pos];

    double bd = 1e300; int bi = 0x7FFFFFFF;
    while (mask) {
        int c = __ffsll((long long)mask) - 1;
        mask &= mask - 1;
        #pragma unroll
        for (int r = 0; r < KCH/64; ++r) {
            int k = c*KCH + r*64 + lane;
            const double* cp = cb_n + (size_t)k*DCB;
            double dot = e[0]*cp[0] + e[1]*cp[1] + e[2]*cp[2] + e[3]*cp[3]
                       + e[4]*cp[4] + e[5]*cp[5] + e[6]*cp[6] + e[7]*cp[7];
            double dist = qs - 2.0*dot + s_k[k];
            if (dist < bd || (dist == bd && k < bi)) { bd = dist; bi = k; }
        }
    }
    #pragma unroll
    for (int off = 1; off < 64; off <<= 1) {
        double od = __shfl_xor(bd, off, 64);
        int    oi = __shfl_xor(bi, off, 64);
        if (od < bd || (od == bd && oi < bi)) { bd = od; bi = oi; }
    }
    if (lane == 0) {
        int b = pos >> 11, t = pos & (TT-1);
        idx_f[pos] = (float)bi;
        idx_i[pos] = bi;
        double ssum = 0.0;
        #pragma unroll
        for (int d = 0; d < DCB; ++d) {
            double zev = (double)ze[((size_t)b*DCB + d)*TT + t];
            double zqv = (double)cb[bi*DCB + d];
            double diff = zev - zqv;
            ssum += diff*diff;
        }
        sred[wv] = ssum;
    }
    __syncthreads();
    if (tid == 0) {
        double t4 = sred[0] + sred[1] + sred[2] + sred[3];
        int b = (blockIdx.x*4) >> 11;     // all 4 pos in a block share b
        atomicAdd(&lacc[b*8 + (blockIdx.x & 7)], t4);
    }
}

// ---------------- kernel 5: out-projection (+ loss finalize) ----------------
// Round-1 shape (128-output chunks, grid (64,8)) — the 64-chunk split regressed.
__global__ __launch_bounds__(256) void k_out_proj(
    const float* __restrict__ cb, const float* __restrict__ ze,
    const int* __restrict__ idx_i, const float* __restrict__ w_out,
    const float* __restrict__ out_b, const double* __restrict__ lacc,
    float* __restrict__ commit_out, float* __restrict__ cbloss_out,
    float* __restrict__ zq_out)
{
    __shared__ float wl[128*DCB];
    __shared__ float bl[128];
    int tid = threadIdx.x;

    if (blockIdx.x == 0 && blockIdx.y == 0 && tid < 8) {
        double s = 0.0;
        #pragma unroll
        for (int j = 0; j < 8; ++j) s += lacc[tid*8 + j];
        double mm = s / (double)(DCB*TT);
        commit_out[tid] = (float)(mm * 0.005);
        cbloss_out[tid] = (float)mm;
    }

    int oc = blockIdx.y;
    int obase = oc*128;
    for (int x = tid; x < 128*DCB; x += 256) wl[x] = w_out[obase*DCB + x];
    for (int x = tid; x < 128; x += 256) bl[x] = out_b[obase + x];
    __syncthreads();

    int pos = blockIdx.x*256 + tid;
    int b = pos >> 11, t = pos & (TT-1);
    int ki = idx_i[pos];
    float zq[DCB];
    #pragma unroll
    for (int d = 0; d < DCB; ++d) {
        float zev = ze[((size_t)b*DCB + d)*TT + t];
        float zqv = cb[ki*DCB + d];
        zq[d] = zev + (zqv - zev);
    }
    float* outp = zq_out + ((size_t)b*DIN + obase)*TT + t;
    for (int oo = 0; oo < 128; ++oo) {
        float acc = 0.f;
        #pragma unroll
        for (int d = 0; d < DCB; ++d) acc += wl[oo*DCB + d]*zq[d];
        acc += bl[oo];
        outp[(size_t)oo*TT] = acc;
    }
}

// ---------------- launch ----------------------------------------------------
extern "C" void kernel_launch(void* const* d_in, const int* in_sizes, int n_in,
                              void* d_out, int out_size, void* d_ws, size_t ws_size,
                              hipStream_t stream)
{
    const float* z        = (const float*)d_in[0];
    const float* in_v     = (const float*)d_in[1];
    const float* in_g     = (const float*)d_in[2];
    const float* in_b     = (const float*)d_in[3];
    const float* out_v    = (const float*)d_in[4];
    const float* out_g    = (const float*)d_in[5];
    const float* out_b    = (const float*)d_in[6];
    const float* codebook = (const float*)d_in[7];

    float* out = (float*)d_out;
    float* zq_out_p  = out + OFF_ZQOUT;
    float* commit_p  = out + OFF_COMMIT;
    float* cbloss_p  = out + OFF_CBLOSS;
    float* idx_p     = out + OFF_IDX;
    float* ze_p      = out + OFF_ZE;

    // workspace layout (doubles first; w_in slot holds fp32 [i][o] weights)
    float*  w_in_f = (float*)d_ws;                         // in 8192-dbl slot
    double* cb_n   = (double*)d_ws + DCB*DIN;              // 65536
    double* s_k    = cb_n + (size_t)KK*DCB;                // 8192
    double* enc_n  = s_k + KK;                             // 131072
    double* q_s    = enc_n + (size_t)NPOS*DCB;             // 16384
    double* loss_q = q_s + NPOS;                           // 16384 (slot kept, unused)
    float*  w_out  = (float*)(loss_q + NPOS);              // 8192
    float*  skp_f  = w_out + DCB*DIN;                      // 8192
    unsigned short* cb16  = (unsigned short*)(skp_f + KK); // 131072 ushorts
    unsigned short* enc16 = cb16 + (size_t)KK*16;          // 262144 ushorts
    int*    d1key  = (int*)(enc16 + (size_t)NPOS*16);      // NPOS*64 ints (4 MB)
    int*    idx_i  = d1key + (size_t)NPOS*KCHUNKS;         // 16384
    double* lacc   = (double*)(idx_i + NPOS);              // 64 fp64 loss slots

    k_prep<<<44, 256, 0, stream>>>(in_v, in_g, out_v, out_g, codebook,
                                   w_in_f, w_out, cb_n, s_k, cb16, skp_f, lacc);
    k_inproj<<<NPOS/32, 256, 0, stream>>>(z, w_in_f, in_b, ze_p, enc_n, q_s, enc16);
    k_screen<<<dim3(NPOS/256, KCHUNKS/SCR_CB), 256, 0, stream>>>(
        enc16, cb16, skp_f, d1key);
    k_verify<<<NPOS/4, 256, 0, stream>>>(d1key, enc_n, q_s, cb_n, s_k,
                                         codebook, ze_p, idx_p, idx_i, lacc);
    k_out_proj<<<dim3(NPOS/256, DIN/128), 256, 0, stream>>>(
        codebook, ze_p, idx_i, w_out, out_b, lacc, commit_p, cbloss_p, zq_out_p);
}